// Round 1
// baseline (2930.946 us; speedup 1.0000x reference)
//
#include <hip/hip_runtime.h>
#include <math.h>

// Problem constants
#define NB    64
#define CIN   256
#define OC    256
#define ICN   257      // CIN + 1 (dist channel)
#define NCLS  80
#define KCLS  16384    // OC*8*8
#define KREG  262144   // OC*32*32

// workspace layout (float offsets). Total 21,043,200 floats = 84.2 MB.
#define WS_DS_ENC 0          // 4096 (unsigned encodings of max_q d)
#define WS_DT     4096       // 65536 (dist_t, transformed)
#define WS_YCLS   69632      // 4194304 (raw conv_cls output)
#define WS_YREG   4263936    // 16777216 (raw conv_reg output)
#define WS_SUMS   21041152   // 1024: [sum_cls][sumsq_cls][sum_reg][sumsq_reg]
#define WS_SS     21042176   // 1024: [scale_cls][shift_cls][scale_reg][shift_reg]

__device__ __forceinline__ float dsig(float d) {
    // 4*sigmoid(-d) - 1 ; monotone DECREASING in d (so min over t == t(max d))
    return 4.0f / (1.0f + __expf(d)) - 1.0f;
}
// order-preserving float<->uint encoding (unsigned compare == float compare)
__device__ __forceinline__ unsigned fenc(float f) {
    unsigned u = __float_as_uint(f);
    return (u & 0x80000000u) ? ~u : (u | 0x80000000u);
}
__device__ __forceinline__ float fdec(unsigned e) {
    unsigned u = (e & 0x80000000u) ? (e ^ 0x80000000u) : ~e;
    return __uint_as_float(u);
}

// ---------------------------------------------------------------- init
// d_out/d_ws are re-poisoned 0xAA before every timed call: seed everything
// that is accumulated into atomically.
__global__ void k_init(unsigned* __restrict__ ds_enc, float* __restrict__ sums,
                       float* __restrict__ out_loc, const float* __restrict__ lin_reg_b) {
    int i = blockIdx.x * 256 + threadIdx.x;
    if (i < 4096) ds_enc[i] = 0u;          // smallest encoding == -inf (we take max)
    if (i < 1024) sums[i] = 0.0f;
    if (i < 20480) out_loc[i] = lin_reg_b[i % 320];   // bias seed for atomic split-K
}

// ---------------------------------------------------------------- dist
// grid (4 q-blocks, 64 n), block 256. Thread owns one q; 64 dot-accumulators
// over p. z reads are lane-invariant -> scalar loads (SMEM pipe), x reads
// coalesced. dist_t = t(max_p d) thread-local; dist_s via wave max + atomicMax.
__global__ __launch_bounds__(256) void k_dist(const float* __restrict__ z, const float* __restrict__ x,
                                              float* __restrict__ dist_t, unsigned* __restrict__ ds_enc) {
    __shared__ float zsq_s[64];
    const int n = blockIdx.y;
    const int q = (blockIdx.x << 8) + threadIdx.x;
    const float* zb = z + n * 16384;
    const float* xb = x + n * 262144;

    if (threadIdx.x < 64) {   // wave 0: zsq[p], coalesced 256B per c
        int p = threadIdx.x;
        float s = 0.f;
        for (int c = 0; c < 256; ++c) { float v = zb[c * 64 + p]; s = fmaf(v, v, s); }
        zsq_s[p] = s;
    }
    __syncthreads();

    float4 acc[16];
#pragma unroll
    for (int i = 0; i < 16; ++i) acc[i] = make_float4(0.f, 0.f, 0.f, 0.f);
    float xsq = 0.f;
    for (int c = 0; c < 256; ++c) {
        float xv = xb[c * 1024 + q];
        xsq = fmaf(xv, xv, xsq);
        const float4* z4 = reinterpret_cast<const float4*>(zb + c * 64);  // uniform -> s_load
#pragma unroll
        for (int i = 0; i < 16; ++i) {
            float4 zv = z4[i];
            acc[i].x = fmaf(zv.x, xv, acc[i].x);
            acc[i].y = fmaf(zv.y, xv, acc[i].y);
            acc[i].z = fmaf(zv.z, xv, acc[i].z);
            acc[i].w = fmaf(zv.w, xv, acc[i].w);
        }
    }

    const int lane = threadIdx.x & 63;
    float dmax = -1e30f;
    auto do_p = [&](int p, float a) {
        float dr = zsq_s[p] + xsq - 2.f * a;   // raw squared distance
        dmax = fmaxf(dmax, dr);
        float m = dr;                           // wave-max over q for this p
#pragma unroll
        for (int off = 1; off < 64; off <<= 1) m = fmaxf(m, __shfl_xor(m, off));
        if (lane == 0) atomicMax(&ds_enc[n * 64 + p], fenc(m));
    };
#pragma unroll
    for (int i = 0; i < 16; ++i) {
        do_p(4 * i + 0, acc[i].x);
        do_p(4 * i + 1, acc[i].y);
        do_p(4 * i + 2, acc[i].z);
        do_p(4 * i + 3, acc[i].w);
    }
    dist_t[n * 1024 + q] = dsig(dmax);   // transformed, ready for conv_reg ch0
}

// ---------------------------------------------------------------- conv_cls (8x8)
// grid (32 oc-blocks, 64 n), block 256 = 64 pos x 4 waves; wave g owns oc pair.
__global__ __launch_bounds__(256) void k_conv_cls(const float* __restrict__ zf, const unsigned* __restrict__ ds_enc,
                                                  const float* __restrict__ w, float* __restrict__ y,
                                                  float* __restrict__ sums) {
    __shared__ __align__(16) float tile[4][100];
    __shared__ __align__(16) float ws_[4][8][12];
    const int oc0 = blockIdx.x * 8;
    const int n = blockIdx.y;
    const int tid = threadIdx.x;
    const int pos = tid & 63, g = tid >> 6;
    const int py = pos >> 3, px = pos & 7;
    float acc0 = 0.f, acc1 = 0.f;

    auto compute_ic = [&](const float* t, const float wsl[8][12]) {
        float in9[9];
#pragma unroll
        for (int ky = 0; ky < 3; ++ky)
#pragma unroll
            for (int kx = 0; kx < 3; ++kx)
                in9[ky * 3 + kx] = t[(py + ky) * 10 + px + kx];
#pragma unroll
        for (int j = 0; j < 2; ++j) {
            const float* wp = wsl[g * 2 + j];
            float s = 0.f;
#pragma unroll
            for (int kk = 0; kk < 9; ++kk) s = fmaf(in9[kk], wp[kk], s);
            if (j == 0) acc0 += s; else acc1 += s;
        }
    };

    // ic = 0 (dist_s channel: decode + transform here)
    if (tid < 100) {
        int yy = tid / 10, xx = tid % 10;
        float v = 0.f;
        if (yy >= 1 && yy <= 8 && xx >= 1 && xx <= 8)
            v = dsig(fdec(ds_enc[n * 64 + (yy - 1) * 8 + (xx - 1)]));
        tile[0][tid] = v;
    }
    if (tid < 72) {
        int ocl = tid / 9, kk = tid % 9;
        ws_[0][ocl][kk] = w[((oc0 + ocl) * 257 + 0) * 9 + kk];
    }
    __syncthreads();
    compute_ic(tile[0], ws_[0]);

    for (int cc = 0; cc < 64; ++cc) {
        __syncthreads();
        for (int e = tid; e < 400; e += 256) {
            int icl = e / 100, rem = e % 100;
            int yy = rem / 10, xx = rem % 10;
            float v = 0.f;
            if (yy >= 1 && yy <= 8 && xx >= 1 && xx <= 8)
                v = zf[n * 16384 + (cc * 4 + icl) * 64 + (yy - 1) * 8 + (xx - 1)];
            tile[icl][rem] = v;
        }
        for (int e = tid; e < 288; e += 256) {
            int icl = e / 72, rem = e % 72;
            int ocl = rem / 9, kk = rem % 9;
            ws_[icl][ocl][kk] = w[((oc0 + ocl) * 257 + 1 + cc * 4 + icl) * 9 + kk];
        }
        __syncthreads();
#pragma unroll
        for (int icl = 0; icl < 4; ++icl) compute_ic(tile[icl], ws_[icl]);
    }

    y[n * 16384 + (oc0 + g * 2 + 0) * 64 + pos] = acc0;
    y[n * 16384 + (oc0 + g * 2 + 1) * 64 + pos] = acc1;

    // BN batch stats: wave-reduce (one n, 64 positions) then atomicAdd
    const int lane = tid & 63;
    float s0 = acc0, q0 = acc0 * acc0, s1 = acc1, q1 = acc1 * acc1;
#pragma unroll
    for (int off = 1; off < 64; off <<= 1) {
        s0 += __shfl_xor(s0, off); q0 += __shfl_xor(q0, off);
        s1 += __shfl_xor(s1, off); q1 += __shfl_xor(q1, off);
    }
    if (lane == 0) {
        atomicAdd(&sums[0 + oc0 + g * 2 + 0], s0);
        atomicAdd(&sums[256 + oc0 + g * 2 + 0], q0);
        atomicAdd(&sums[0 + oc0 + g * 2 + 1], s1);
        atomicAdd(&sums[256 + oc0 + g * 2 + 1], q1);
    }
}

// ---------------------------------------------------------------- conv_reg (32x32)
// grid (32 oc-blocks, 64 n), block 256; thread = 4 positions x 8 oc (32 acc).
__global__ __launch_bounds__(256) void k_conv_reg(const float* __restrict__ xf, const float* __restrict__ dist_t,
                                                  const float* __restrict__ w, float* __restrict__ y,
                                                  float* __restrict__ sums) {
    __shared__ __align__(16) float tile[4][1156];
    __shared__ __align__(16) float ws_[4][8][12];
    __shared__ float wredS[4][8], wredQ[4][8];
    const int oc0 = blockIdx.x * 8;
    const int n = blockIdx.y;
    const int tid = threadIdx.x;
    const int px = tid & 31, py0 = tid >> 5;   // pos = (py0+8*pp)*32 + px
    float acc[4][8];
#pragma unroll
    for (int a = 0; a < 4; ++a)
#pragma unroll
        for (int b = 0; b < 8; ++b) acc[a][b] = 0.f;

    auto compute_ic = [&](const float* t, const float wsl[8][12]) {
        float in_v[4][9];
#pragma unroll
        for (int pp = 0; pp < 4; ++pp)
#pragma unroll
            for (int ky = 0; ky < 3; ++ky)
#pragma unroll
                for (int kx = 0; kx < 3; ++kx)
                    in_v[pp][ky * 3 + kx] = t[(py0 + 8 * pp + ky) * 34 + px + kx];
#pragma unroll
        for (int ocl = 0; ocl < 8; ++ocl) {
            const float4* wp4 = reinterpret_cast<const float4*>(&wsl[ocl][0]);
            float4 wA = wp4[0], wB = wp4[1];
            float w8 = wsl[ocl][8];
#pragma unroll
            for (int pp = 0; pp < 4; ++pp) {
                float s = acc[pp][ocl];
                s = fmaf(in_v[pp][0], wA.x, s);
                s = fmaf(in_v[pp][1], wA.y, s);
                s = fmaf(in_v[pp][2], wA.z, s);
                s = fmaf(in_v[pp][3], wA.w, s);
                s = fmaf(in_v[pp][4], wB.x, s);
                s = fmaf(in_v[pp][5], wB.y, s);
                s = fmaf(in_v[pp][6], wB.z, s);
                s = fmaf(in_v[pp][7], wB.w, s);
                s = fmaf(in_v[pp][8], w8, s);
                acc[pp][ocl] = s;
            }
        }
    };

    // ic = 0 (dist_t channel, already transformed)
    for (int e = tid; e < 1156; e += 256) {
        int yy = e / 34, xx = e % 34;
        float v = 0.f;
        if (yy >= 1 && yy <= 32 && xx >= 1 && xx <= 32)
            v = dist_t[n * 1024 + (yy - 1) * 32 + (xx - 1)];
        tile[0][e] = v;
    }
    if (tid < 72) {
        int ocl = tid / 9, kk = tid % 9;
        ws_[0][ocl][kk] = w[((oc0 + ocl) * 257 + 0) * 9 + kk];
    }
    __syncthreads();
    compute_ic(tile[0], ws_[0]);

    for (int cc = 0; cc < 64; ++cc) {
        __syncthreads();
        for (int e = tid; e < 4624; e += 256) {
            int icl = e / 1156, rem = e % 1156;
            int yy = rem / 34, xx = rem % 34;
            float v = 0.f;
            if (yy >= 1 && yy <= 32 && xx >= 1 && xx <= 32)
                v = xf[n * 262144 + (cc * 4 + icl) * 1024 + (yy - 1) * 32 + (xx - 1)];
            tile[icl][rem] = v;
        }
        for (int e = tid; e < 288; e += 256) {
            int icl = e / 72, rem = e % 72, ocl = rem / 9, kk = rem % 9;
            ws_[icl][ocl][kk] = w[((oc0 + ocl) * 257 + 1 + cc * 4 + icl) * 9 + kk];
        }
        __syncthreads();
#pragma unroll
        for (int icl = 0; icl < 4; ++icl) compute_ic(tile[icl], ws_[icl]);
    }

#pragma unroll
    for (int pp = 0; pp < 4; ++pp)
#pragma unroll
        for (int ocl = 0; ocl < 8; ++ocl)
            y[n * 262144 + (oc0 + ocl) * 1024 + (py0 + 8 * pp) * 32 + px] = acc[pp][ocl];

    const int lane = tid & 63, wid = tid >> 6;
#pragma unroll
    for (int ocl = 0; ocl < 8; ++ocl) {
        float s = acc[0][ocl] + acc[1][ocl] + acc[2][ocl] + acc[3][ocl];
        float qq = acc[0][ocl] * acc[0][ocl] + acc[1][ocl] * acc[1][ocl] +
                   acc[2][ocl] * acc[2][ocl] + acc[3][ocl] * acc[3][ocl];
#pragma unroll
        for (int off = 1; off < 64; off <<= 1) {
            s += __shfl_xor(s, off);
            qq += __shfl_xor(qq, off);
        }
        if (lane == 0) { wredS[wid][ocl] = s; wredQ[wid][ocl] = qq; }
    }
    __syncthreads();
    if (tid < 8) {
        float S = wredS[0][tid] + wredS[1][tid] + wredS[2][tid] + wredS[3][tid];
        float Q = wredQ[0][tid] + wredQ[1][tid] + wredQ[2][tid] + wredQ[3][tid];
        atomicAdd(&sums[512 + oc0 + tid], S);
        atomicAdd(&sums[768 + oc0 + tid], Q);
    }
}

// ---------------------------------------------------------------- BN finalize
__global__ void k_bnfin(const float* __restrict__ sums,
                        const float* __restrict__ g_cls, const float* __restrict__ b_cls,
                        const float* __restrict__ g_reg, const float* __restrict__ b_reg,
                        float* __restrict__ ss) {
    int t = threadIdx.x;   // 256
    {
        float mean = sums[t] * (1.f / 4096.f);
        float var = sums[256 + t] * (1.f / 4096.f) - mean * mean;
        float sc = g_cls[t] * rsqrtf(var + 1e-5f);
        ss[t] = sc;
        ss[256 + t] = b_cls[t] - mean * sc;
    }
    {
        float mean = sums[512 + t] * (1.f / 65536.f);
        float var = sums[768 + t] * (1.f / 65536.f) - mean * mean;
        float sc = g_reg[t] * rsqrtf(var + 1e-5f);
        ss[512 + t] = sc;
        ss[768 + t] = b_reg[t] - mean * sc;
    }
}

// ---------------------------------------------------------------- lin_cls
// grid (5 j-tiles, 64 n); full K per block -> direct store with bias.
__global__ __launch_bounds__(256) void k_lin_cls(const float* __restrict__ y, const float* __restrict__ ss,
                                                 const float* __restrict__ w, const float* __restrict__ bias,
                                                 float* __restrict__ out) {
    const int jt = blockIdx.x, n = blockIdx.y, j0 = jt * 16;
    const int tid = threadIdx.x;
    float part[16];
#pragma unroll
    for (int j = 0; j < 16; ++j) part[j] = 0.f;

    for (int s = 0; s < 16; ++s) {
        int k4 = (s * 256 + tid) * 4;
        float4 yv = *reinterpret_cast<const float4*>(&y[n * 16384 + k4]);
        int ch = k4 >> 6;                                  // same ch for all 4 lanes of k4
        float sc = ss[ch], sh = ss[256 + ch];
        float ax = fmaxf(fmaf(yv.x, sc, sh), 0.f);
        float ay = fmaxf(fmaf(yv.y, sc, sh), 0.f);
        float az = fmaxf(fmaf(yv.z, sc, sh), 0.f);
        float aw = fmaxf(fmaf(yv.w, sc, sh), 0.f);
#pragma unroll
        for (int j = 0; j < 16; ++j) {
            float4 wv = *reinterpret_cast<const float4*>(&w[(j0 + j) * 16384 + k4]);
            float p = part[j];
            p = fmaf(ax, wv.x, p);
            p = fmaf(ay, wv.y, p);
            p = fmaf(az, wv.z, p);
            p = fmaf(aw, wv.w, p);
            part[j] = p;
        }
    }
    __shared__ float red[16][4];
    const int lane = tid & 63, wid = tid >> 6;
#pragma unroll
    for (int j = 0; j < 16; ++j) {
        float v = part[j];
#pragma unroll
        for (int off = 1; off < 64; off <<= 1) v += __shfl_xor(v, off);
        if (lane == 0) red[j][wid] = v;
    }
    __syncthreads();
    if (tid < 16)
        out[n * 80 + j0 + tid] = red[tid][0] + red[tid][1] + red[tid][2] + red[tid][3] + bias[j0 + tid];
}

// ---------------------------------------------------------------- lin_reg
// grid 512 = 2 j-tiles(160) x 256 k-splits(1024). w read exactly once (335 MB).
// thread = 5 j x 8 n accumulators; LDS tiles stride 65 (conflict-free b32).
__global__ __launch_bounds__(256) void k_lin_reg(const float* __restrict__ y, const float* __restrict__ ss,
                                                 const float* __restrict__ w, float* __restrict__ out_loc) {
    __shared__ float a_s[64 * 65];
    __shared__ float w_s[160 * 65];
    const int jt = blockIdx.x & 1, ks = blockIdx.x >> 1;
    const int j0 = jt * 160, k0 = ks * 1024;
    const int tid = threadIdx.x;
    const int tj = tid & 31, tn = tid >> 5;
    float acc[5][8];
#pragma unroll
    for (int a = 0; a < 5; ++a)
#pragma unroll
        for (int b = 0; b < 8; ++b) acc[a][b] = 0.f;

    for (int st = 0; st < 16; ++st) {
        const int kb = k0 + st * 64;
        __syncthreads();
        // stage A (normalized relu activations): 64 n x 64 k
#pragma unroll
        for (int r = 0; r < 4; ++r) {
            int f = tid + 256 * r;
            int nn = f >> 4, kk4 = (f & 15) * 4;
            float4 yv = *reinterpret_cast<const float4*>(&y[nn * 262144 + kb + kk4]);
            int ch = (kb + kk4) >> 10;
            float sc = ss[512 + ch], sh = ss[768 + ch];
            float* dst = &a_s[nn * 65 + kk4];
            dst[0] = fmaxf(fmaf(yv.x, sc, sh), 0.f);
            dst[1] = fmaxf(fmaf(yv.y, sc, sh), 0.f);
            dst[2] = fmaxf(fmaf(yv.z, sc, sh), 0.f);
            dst[3] = fmaxf(fmaf(yv.w, sc, sh), 0.f);
        }
        // stage W: 160 j x 64 k
#pragma unroll
        for (int r = 0; r < 10; ++r) {
            int f = tid + 256 * r;
            int jl = f >> 4, kk4 = (f & 15) * 4;
            float4 wv = *reinterpret_cast<const float4*>(&w[(size_t)(j0 + jl) * 262144 + kb + kk4]);
            float* dst = &w_s[jl * 65 + kk4];
            dst[0] = wv.x; dst[1] = wv.y; dst[2] = wv.z; dst[3] = wv.w;
        }
        __syncthreads();
#pragma unroll 4
        for (int kk = 0; kk < 64; ++kk) {
            float av[8];
#pragma unroll
            for (int ii = 0; ii < 8; ++ii) av[ii] = a_s[(tn * 8 + ii) * 65 + kk];
#pragma unroll
            for (int jj = 0; jj < 5; ++jj) {
                float wvv = w_s[(tj + 32 * jj) * 65 + kk];
#pragma unroll
                for (int ii = 0; ii < 8; ++ii)
                    acc[jj][ii] = fmaf(wvv, av[ii], acc[jj][ii]);
            }
        }
    }
#pragma unroll
    for (int jj = 0; jj < 5; ++jj)
#pragma unroll
        for (int ii = 0; ii < 8; ++ii)
            atomicAdd(&out_loc[(tn * 8 + ii) * 320 + j0 + tj + 32 * jj], acc[jj][ii]);
}

// ---------------------------------------------------------------- launch
extern "C" void kernel_launch(void* const* d_in, const int* in_sizes, int n_in,
                              void* d_out, int out_size, void* d_ws, size_t ws_size,
                              hipStream_t stream) {
    const float* z_f        = (const float*)d_in[0];
    const float* x_f        = (const float*)d_in[1];
    const float* conv_cls_w = (const float*)d_in[2];
    const float* bn_cls_g   = (const float*)d_in[3];
    const float* bn_cls_b   = (const float*)d_in[4];
    const float* conv_reg_w = (const float*)d_in[5];
    const float* bn_reg_g   = (const float*)d_in[6];
    const float* bn_reg_b   = (const float*)d_in[7];
    const float* lin_cls_w  = (const float*)d_in[8];
    const float* lin_cls_b  = (const float*)d_in[9];
    const float* lin_reg_w  = (const float*)d_in[10];
    const float* lin_reg_b  = (const float*)d_in[11];

    float* out = (float*)d_out;
    float* ws  = (float*)d_ws;
    unsigned* ds_enc = (unsigned*)(ws + WS_DS_ENC);
    float* dist_t = ws + WS_DT;
    float* y_cls  = ws + WS_YCLS;
    float* y_reg  = ws + WS_YREG;
    float* sums   = ws + WS_SUMS;
    float* ss     = ws + WS_SS;

    hipLaunchKernelGGL(k_init, dim3(80), dim3(256), 0, stream, ds_enc, sums, out + 5120, lin_reg_b);
    hipLaunchKernelGGL(k_dist, dim3(4, 64), dim3(256), 0, stream, z_f, x_f, dist_t, ds_enc);
    hipLaunchKernelGGL(k_conv_cls, dim3(32, 64), dim3(256), 0, stream, z_f, ds_enc, conv_cls_w, y_cls, sums);
    hipLaunchKernelGGL(k_conv_reg, dim3(32, 64), dim3(256), 0, stream, x_f, dist_t, conv_reg_w, y_reg, sums);
    hipLaunchKernelGGL(k_bnfin, dim3(1), dim3(256), 0, stream, sums, bn_cls_g, bn_cls_b, bn_reg_g, bn_reg_b, ss);
    hipLaunchKernelGGL(k_lin_cls, dim3(5, 64), dim3(256), 0, stream, y_cls, ss, lin_cls_w, lin_cls_b, out);
    hipLaunchKernelGGL(k_lin_reg, dim3(512), dim3(256), 0, stream, y_reg, ss, lin_reg_w, out + 5120);
}

// Round 2
// 965.533 us; speedup vs baseline: 3.0356x; 3.0356x over previous
//
#include <hip/hip_runtime.h>
#include <math.h>

typedef short short8 __attribute__((ext_vector_type(8)));
typedef float f32x4 __attribute__((ext_vector_type(4)));

// ---------------- workspace layout (float offsets) ----------------
#define WS_DS_ENC 0            // 4096 u32
#define WS_DT     4096         // 65536 f32
#define WS_SUMS   69632        // 1024 f32
#define WS_SS     70656        // 1024 f32
#define WS_YCLS   71680        // 1,048,576 ushort (524288 fl)  [n][256][64] bf16
#define WS_YREG   595968       // 16,777,216 ushort (8388608 fl) [n][256][1024] bf16
#define WS_XT     8984576      // 16,777,216 ushort  [n][32][32][256] bf16
#define WS_ZT     17373184     // 1,048,576 ushort   [n][64][256] bf16
#define WS_WTR    17897472     // 589,824 ushort  [9][8][4][256][8]
#define WS_WTDR   18192384     // 8,192 ushort    [4][256][8]
#define WS_WTC    18196480     // 589,824 ushort
#define WS_WTDC   18491392     // 8,192 ushort
// end: 18,495,488 floats = 74.0 MB

__device__ __forceinline__ float dsig(float d) {
    return 4.0f / (1.0f + __expf(d)) - 1.0f;   // monotone decreasing
}
__device__ __forceinline__ unsigned fenc(float f) {
    unsigned u = __float_as_uint(f);
    return (u & 0x80000000u) ? ~u : (u | 0x80000000u);
}
__device__ __forceinline__ float fdec(unsigned e) {
    unsigned u = (e & 0x80000000u) ? (e ^ 0x80000000u) : ~e;
    return __uint_as_float(u);
}
__device__ __forceinline__ unsigned short f2bf(float f) {   // RNE
    unsigned u = __float_as_uint(f);
    return (unsigned short)((u + 0x7fffu + ((u >> 16) & 1u)) >> 16);
}
__device__ __forceinline__ float bf2f(unsigned short h) {
    return __uint_as_float(((unsigned)h) << 16);
}

// ---------------------------------------------------------------- init
__global__ void k_init(unsigned* __restrict__ ds_enc, float* __restrict__ sums,
                       float* __restrict__ out_loc, const float* __restrict__ lin_reg_b) {
    int i = blockIdx.x * 256 + threadIdx.x;
    if (i < 4096) ds_enc[i] = 0u;
    if (i < 1024) sums[i] = 0.0f;
    if (i < 20480) out_loc[i] = lin_reg_b[i % 320];
}

// ---------------------------------------------------------------- transposes
// xt[n][row][col][ic] bf16 (no halo; bounds handled at staging)
__global__ __launch_bounds__(256) void k_xt(const float* __restrict__ x, unsigned short* __restrict__ xt) {
    __shared__ float t[64 * 33];
    const int n = blockIdx.x, row = blockIdx.y;
    const int tid = threadIdx.x;
    for (int c4 = 0; c4 < 4; ++c4) {
        const int ic0 = c4 * 64;
        __syncthreads();
        {
            int icl = tid >> 2, cg = tid & 3;
            const float* src = &x[((n * 256 + ic0 + icl) * 32 + row) * 32 + cg * 8];
            float4 a = *reinterpret_cast<const float4*>(src);
            float4 b = *reinterpret_cast<const float4*>(src + 4);
            float* d = &t[icl * 33 + cg * 8];
            d[0] = a.x; d[1] = a.y; d[2] = a.z; d[3] = a.w;
            d[4] = b.x; d[5] = b.y; d[6] = b.z; d[7] = b.w;
        }
        __syncthreads();
        {
            int col = tid & 31, g = tid >> 5;
            short8 v;
#pragma unroll
            for (int j = 0; j < 8; ++j) v[j] = (short)f2bf(t[(g * 8 + j) * 33 + col]);
            *reinterpret_cast<short8*>(&xt[((n * 32 + row) * 32 + col) * 256 + ic0 + g * 8]) = v;
        }
    }
}

// zt[n][pos][ic] bf16
__global__ __launch_bounds__(256) void k_zt(const float* __restrict__ z, unsigned short* __restrict__ zt) {
    __shared__ float t[64 * 65];
    const int n = blockIdx.x;
    const int tid = threadIdx.x;
    for (int c4 = 0; c4 < 4; ++c4) {
        const int ic0 = c4 * 64;
        __syncthreads();
        {
            int icl = tid >> 2, pg = tid & 3;
            const float* src = &z[(n * 256 + ic0 + icl) * 64 + pg * 16];
#pragma unroll
            for (int r = 0; r < 4; ++r) {
                float4 a = *reinterpret_cast<const float4*>(src + r * 4);
                float* d = &t[icl * 65 + pg * 16 + r * 4];
                d[0] = a.x; d[1] = a.y; d[2] = a.z; d[3] = a.w;
            }
        }
        __syncthreads();
        {
            int pos = tid & 63, gg = tid >> 6;
            short8 v0, v1;
#pragma unroll
            for (int j = 0; j < 8; ++j) v0[j] = (short)f2bf(t[(gg * 16 + j) * 65 + pos]);
#pragma unroll
            for (int j = 0; j < 8; ++j) v1[j] = (short)f2bf(t[(gg * 16 + 8 + j) * 65 + pos]);
            unsigned short* d = &zt[(n * 64 + pos) * 256 + ic0 + gg * 16];
            *reinterpret_cast<short8*>(d) = v0;
            *reinterpret_cast<short8*>(d + 8) = v1;
        }
    }
}

// ---------------------------------------------------------------- weight swizzle
// wt[tap][kc][q][oc][j]  (k = kc*32 + q*8 + j -> ic = 1 + k) ; wtd[q][oc][j] (k<9 -> tap k, ic 0)
__global__ void k_wswz(const float* __restrict__ wr, const float* __restrict__ wc,
                       unsigned short* __restrict__ wtr, unsigned short* __restrict__ wtdr,
                       unsigned short* __restrict__ wtc, unsigned short* __restrict__ wtdc) {
    const int idx = blockIdx.x * 256 + threadIdx.x;
    const float* src = blockIdx.y ? wc : wr;
    unsigned short* dw = blockIdx.y ? wtc : wtr;
    unsigned short* dd = blockIdx.y ? wtdc : wtdr;
    if (idx < 73728) {
        int tap = idx >> 13, rem = idx & 8191;
        int kc = rem >> 10, rem2 = rem & 1023;
        int q = rem2 >> 8, oc = rem2 & 255;
        short8 v;
#pragma unroll
        for (int j = 0; j < 8; ++j) {
            int icg = 1 + kc * 32 + q * 8 + j;
            v[j] = (short)f2bf(src[(oc * 257 + icg) * 9 + tap]);
        }
        *reinterpret_cast<short8*>(&dw[idx * 8]) = v;
    } else if (idx < 74752) {
        int i2 = idx - 73728;
        int q = i2 >> 8, oc = i2 & 255;
        short8 v;
#pragma unroll
        for (int j = 0; j < 8; ++j) {
            int k = q * 8 + j;
            v[j] = (k < 9) ? (short)f2bf(src[(oc * 257) * 9 + k]) : (short)0;
        }
        *reinterpret_cast<short8*>(&dd[i2 * 8]) = v;
    }
}

// ---------------------------------------------------------------- dist
__global__ __launch_bounds__(256) void k_dist(const float* __restrict__ z, const float* __restrict__ x,
                                              float* __restrict__ dist_t, unsigned* __restrict__ ds_enc) {
    __shared__ float zsq_s[64];
    const int n = blockIdx.y;
    const int q = (blockIdx.x << 8) + threadIdx.x;
    const float* zb = z + n * 16384;
    const float* xb = x + n * 262144;

    if (threadIdx.x < 64) {
        int p = threadIdx.x;
        float s = 0.f;
        for (int c = 0; c < 256; ++c) { float v = zb[c * 64 + p]; s = fmaf(v, v, s); }
        zsq_s[p] = s;
    }
    __syncthreads();

    float4 acc[16];
#pragma unroll
    for (int i = 0; i < 16; ++i) acc[i] = make_float4(0.f, 0.f, 0.f, 0.f);
    float xsq = 0.f;
    for (int c = 0; c < 256; ++c) {
        float xv = xb[c * 1024 + q];
        xsq = fmaf(xv, xv, xsq);
        const float4* z4 = reinterpret_cast<const float4*>(zb + c * 64);
#pragma unroll
        for (int i = 0; i < 16; ++i) {
            float4 zv = z4[i];
            acc[i].x = fmaf(zv.x, xv, acc[i].x);
            acc[i].y = fmaf(zv.y, xv, acc[i].y);
            acc[i].z = fmaf(zv.z, xv, acc[i].z);
            acc[i].w = fmaf(zv.w, xv, acc[i].w);
        }
    }

    const int lane = threadIdx.x & 63;
    float dmax = -1e30f;
    auto do_p = [&](int p, float a) {
        float dr = zsq_s[p] + xsq - 2.f * a;
        dmax = fmaxf(dmax, dr);
        float m = dr;
#pragma unroll
        for (int off = 1; off < 64; off <<= 1) m = fmaxf(m, __shfl_xor(m, off));
        if (lane == 0) atomicMax(&ds_enc[n * 64 + p], fenc(m));
    };
#pragma unroll
    for (int i = 0; i < 16; ++i) {
        do_p(4 * i + 0, acc[i].x);
        do_p(4 * i + 1, acc[i].y);
        do_p(4 * i + 2, acc[i].z);
        do_p(4 * i + 3, acc[i].w);
    }
    dist_t[n * 1024 + q] = dsig(dmax);
}

// ---------------------------------------------------------------- conv_reg MFMA
// block: (pt,ot,n): 128 pos (rows pt*4..+3) x 128 oc. 4 waves 2x2: wave = 64 pos x 64 oc.
__global__ __launch_bounds__(256) void k_conv_reg(
    const unsigned short* __restrict__ xt, const float* __restrict__ dist_t,
    const unsigned short* __restrict__ wt, const unsigned short* __restrict__ wtd,
    unsigned short* __restrict__ y, float* __restrict__ sums) {
    __shared__ __align__(16) char smem[17408];
    unsigned short* As = (unsigned short*)smem;              // 204*40
    unsigned short* Ds = (unsigned short*)(smem + 16320);    // 204
    float* Ts = (float*)smem;                                // 4*1088 after barrier

    const int n = blockIdx.y;
    const int pt = blockIdx.x >> 1, ot = blockIdx.x & 1;
    const int tid = threadIdx.x;
    const int w = tid >> 6, lane = tid & 63;
    const int l15 = lane & 15, q = lane >> 4;
    const int wm = w & 1, wn = w >> 1;
    const int ocW = ot * 128 + wn * 64;

    f32x4 acc[4][4];
#pragma unroll
    for (int mi = 0; mi < 4; ++mi)
#pragma unroll
        for (int ni = 0; ni < 4; ++ni) acc[mi][ni] = (f32x4){0.f, 0.f, 0.f, 0.f};

    // ---- dist pseudo-tap ----
    for (int f = tid; f < 204; f += 256) {
        int rr = f / 34, cc = f % 34;
        int prow = pt * 4 + rr;
        float v = 0.f;
        if (prow >= 1 && prow <= 32 && cc >= 1 && cc <= 32)
            v = dist_t[n * 1024 + (prow - 1) * 32 + (cc - 1)];
        Ds[f] = f2bf(v);
    }
    __syncthreads();
    {
        short8 ad[4];
#pragma unroll
        for (int mi = 0; mi < 4; ++mi) {
            int m = wm * 64 + mi * 16 + l15;
            int r = m >> 5, c = m & 31;
            short8 v = {0, 0, 0, 0, 0, 0, 0, 0};
#pragma unroll
            for (int j = 0; j < 8; ++j) {
                int k = q * 8 + j;
                if (k < 9) {
                    int ky = k / 3, kx = k % 3;
                    v[j] = (short)Ds[(r + ky) * 34 + (c + kx)];
                }
            }
            ad[mi] = v;
        }
#pragma unroll
        for (int ni = 0; ni < 4; ++ni) {
            short8 b = *reinterpret_cast<const short8*>(&wtd[(q * 256 + ocW + ni * 16 + l15) * 8]);
#pragma unroll
            for (int mi = 0; mi < 4; ++mi)
                acc[mi][ni] = __builtin_amdgcn_mfma_f32_16x16x32_bf16(ad[mi], b, acc[mi][ni], 0, 0, 0);
        }
    }

    // ---- main K loop: 8 ic-chunks x 9 taps ----
    for (int kc = 0; kc < 8; ++kc) {
        __syncthreads();
#pragma unroll
        for (int it = 0; it < 4; ++it) {
            int f = tid + 256 * it;
            if (f < 816) {
                int cell = f >> 2, ch = f & 3;
                int rr = cell / 34, cc = cell % 34;
                int prow = pt * 4 + rr;
                short8 v = {0, 0, 0, 0, 0, 0, 0, 0};
                if (prow >= 1 && prow <= 32 && cc >= 1 && cc <= 32)
                    v = *reinterpret_cast<const short8*>(
                        &xt[((n * 32 + prow - 1) * 32 + cc - 1) * 256 + kc * 32 + ch * 8]);
                *reinterpret_cast<short8*>(&As[cell * 40 + ch * 8]) = v;
            }
        }
        __syncthreads();
#pragma unroll
        for (int tap = 0; tap < 9; ++tap) {
            const int ky = tap / 3, kx = tap % 3;
            short8 a[4];
#pragma unroll
            for (int mi = 0; mi < 4; ++mi) {
                int m = wm * 64 + mi * 16 + l15;
                int r = (m >> 5) + ky, c = (m & 31) + kx;
                a[mi] = *reinterpret_cast<const short8*>(&As[(r * 34 + c) * 40 + q * 8]);
            }
            const unsigned short* wb = wt + (size_t)(((tap * 8 + kc) * 4 + q) * 256) * 8;
#pragma unroll
            for (int ni = 0; ni < 4; ++ni) {
                short8 b = *reinterpret_cast<const short8*>(&wb[(ocW + ni * 16 + l15) * 8]);
#pragma unroll
                for (int mi = 0; mi < 4; ++mi)
                    acc[mi][ni] = __builtin_amdgcn_mfma_f32_16x16x32_bf16(a[mi], b, acc[mi][ni], 0, 0, 0);
            }
        }
    }

    // ---- BN stats ----
#pragma unroll
    for (int ni = 0; ni < 4; ++ni) {
        float s = 0.f, qq = 0.f;
#pragma unroll
        for (int mi = 0; mi < 4; ++mi)
#pragma unroll
            for (int e = 0; e < 4; ++e) {
                float v = acc[mi][ni][e];
                s += v; qq = fmaf(v, v, qq);
            }
        s += __shfl_xor(s, 16); s += __shfl_xor(s, 32);
        qq += __shfl_xor(qq, 16); qq += __shfl_xor(qq, 32);
        if (lane < 16) {
            atomicAdd(&sums[512 + ocW + ni * 16 + l15], s);
            atomicAdd(&sums[768 + ocW + ni * 16 + l15], qq);
        }
    }

    // ---- store (bf16) via per-wave LDS transpose ----
    __syncthreads();
    float* T = Ts + w * 1088;
#pragma unroll
    for (int mi = 0; mi < 4; ++mi) {
#pragma unroll
        for (int ni = 0; ni < 4; ++ni)
#pragma unroll
            for (int e = 0; e < 4; ++e)
                T[(ni * 16 + l15) * 17 + q * 4 + e] = acc[mi][ni][e];
#pragma unroll
        for (int eo = 0; eo < 16; ++eo) {
            int ocl = eo * 4 + q;
            float v = T[ocl * 17 + l15];
            y[(size_t)n * 262144 + (size_t)(ocW + ocl) * 1024 + pt * 128 + wm * 64 + mi * 16 + l15] = f2bf(v);
        }
    }
}

// ---------------------------------------------------------------- conv_cls MFMA
// block: (np, ob): 2 n x 64 pos = 128 M, 128 oc. wave wm -> n, wn -> oc half.
__global__ __launch_bounds__(256) void k_conv_cls(
    const unsigned short* __restrict__ zt, const unsigned* __restrict__ ds_enc,
    const unsigned short* __restrict__ wt, const unsigned short* __restrict__ wtd,
    unsigned short* __restrict__ y, float* __restrict__ sums) {
    __shared__ __align__(16) char smem[17408];
    unsigned short* As = (unsigned short*)smem;              // 200*40
    unsigned short* Ds = (unsigned short*)(smem + 16000);    // 200
    float* Ts = (float*)smem;

    const int n0 = blockIdx.x * 2;
    const int ob = blockIdx.y;
    const int tid = threadIdx.x;
    const int w = tid >> 6, lane = tid & 63;
    const int l15 = lane & 15, q = lane >> 4;
    const int wm = w & 1, wn = w >> 1;
    const int ocW = ob * 128 + wn * 64;

    f32x4 acc[4][4];
#pragma unroll
    for (int mi = 0; mi < 4; ++mi)
#pragma unroll
        for (int ni = 0; ni < 4; ++ni) acc[mi][ni] = (f32x4){0.f, 0.f, 0.f, 0.f};

    // ---- dist pseudo-tap ----
    for (int f = tid; f < 200; f += 256) {
        int n_l = f / 100, rem = f % 100;
        int rr = rem / 10, cc = rem % 10;
        float v = 0.f;
        if (rr >= 1 && rr <= 8 && cc >= 1 && cc <= 8)
            v = dsig(fdec(ds_enc[(n0 + n_l) * 64 + (rr - 1) * 8 + (cc - 1)]));
        Ds[f] = f2bf(v);
    }
    __syncthreads();
    {
        short8 ad[4];
#pragma unroll
        for (int mi = 0; mi < 4; ++mi) {
            int pos = mi * 16 + l15;
            int r = pos >> 3, c = pos & 7;
            short8 v = {0, 0, 0, 0, 0, 0, 0, 0};
#pragma unroll
            for (int j = 0; j < 8; ++j) {
                int k = q * 8 + j;
                if (k < 9) {
                    int ky = k / 3, kx = k % 3;
                    v[j] = (short)Ds[wm * 100 + (r + ky) * 10 + (c + kx)];
                }
            }
            ad[mi] = v;
        }
#pragma unroll
        for (int ni = 0; ni < 4; ++ni) {
            short8 b = *reinterpret_cast<const short8*>(&wtd[(q * 256 + ocW + ni * 16 + l15) * 8]);
#pragma unroll
            for (int mi = 0; mi < 4; ++mi)
                acc[mi][ni] = __builtin_amdgcn_mfma_f32_16x16x32_bf16(ad[mi], b, acc[mi][ni], 0, 0, 0);
        }
    }

    for (int kc = 0; kc < 8; ++kc) {
        __syncthreads();
#pragma unroll
        for (int it = 0; it < 4; ++it) {
            int f = tid + 256 * it;
            if (f < 800) {
                int cell = f >> 2, ch = f & 3;
                int n_l = cell / 100, rem = cell % 100;
                int rr = rem / 10, cc = rem % 10;
                short8 v = {0, 0, 0, 0, 0, 0, 0, 0};
                if (rr >= 1 && rr <= 8 && cc >= 1 && cc <= 8)
                    v = *reinterpret_cast<const short8*>(
                        &zt[((n0 + n_l) * 64 + (rr - 1) * 8 + (cc - 1)) * 256 + kc * 32 + ch * 8]);
                *reinterpret_cast<short8*>(&As[cell * 40 + ch * 8]) = v;
            }
        }
        __syncthreads();
#pragma unroll
        for (int tap = 0; tap < 9; ++tap) {
            const int ky = tap / 3, kx = tap % 3;
            short8 a[4];
#pragma unroll
            for (int mi = 0; mi < 4; ++mi) {
                int pos = mi * 16 + l15;
                int r = (pos >> 3) + ky, c = (pos & 7) + kx;
                a[mi] = *reinterpret_cast<const short8*>(&As[(wm * 100 + r * 10 + c) * 40 + q * 8]);
            }
            const unsigned short* wb = wt + (size_t)(((tap * 8 + kc) * 4 + q) * 256) * 8;
#pragma unroll
            for (int ni = 0; ni < 4; ++ni) {
                short8 b = *reinterpret_cast<const short8*>(&wb[(ocW + ni * 16 + l15) * 8]);
#pragma unroll
                for (int mi = 0; mi < 4; ++mi)
                    acc[mi][ni] = __builtin_amdgcn_mfma_f32_16x16x32_bf16(a[mi], b, acc[mi][ni], 0, 0, 0);
            }
        }
    }

#pragma unroll
    for (int ni = 0; ni < 4; ++ni) {
        float s = 0.f, qq = 0.f;
#pragma unroll
        for (int mi = 0; mi < 4; ++mi)
#pragma unroll
            for (int e = 0; e < 4; ++e) {
                float v = acc[mi][ni][e];
                s += v; qq = fmaf(v, v, qq);
            }
        s += __shfl_xor(s, 16); s += __shfl_xor(s, 32);
        qq += __shfl_xor(qq, 16); qq += __shfl_xor(qq, 32);
        if (lane < 16) {
            atomicAdd(&sums[0 + ocW + ni * 16 + l15], s);
            atomicAdd(&sums[256 + ocW + ni * 16 + l15], qq);
        }
    }

    __syncthreads();
    float* T = Ts + w * 1088;
#pragma unroll
    for (int mi = 0; mi < 4; ++mi) {
#pragma unroll
        for (int ni = 0; ni < 4; ++ni)
#pragma unroll
            for (int e = 0; e < 4; ++e)
                T[(ni * 16 + l15) * 17 + q * 4 + e] = acc[mi][ni][e];
#pragma unroll
        for (int eo = 0; eo < 16; ++eo) {
            int ocl = eo * 4 + q;
            float v = T[ocl * 17 + l15];
            y[(size_t)(n0 + wm) * 16384 + (size_t)(ocW + ocl) * 64 + mi * 16 + l15] = f2bf(v);
        }
    }
}

// ---------------------------------------------------------------- BN finalize
__global__ void k_bnfin(const float* __restrict__ sums,
                        const float* __restrict__ g_cls, const float* __restrict__ b_cls,
                        const float* __restrict__ g_reg, const float* __restrict__ b_reg,
                        float* __restrict__ ss) {
    int t = threadIdx.x;
    {
        float mean = sums[t] * (1.f / 4096.f);
        float var = sums[256 + t] * (1.f / 4096.f) - mean * mean;
        float sc = g_cls[t] * rsqrtf(var + 1e-5f);
        ss[t] = sc;
        ss[256 + t] = b_cls[t] - mean * sc;
    }
    {
        float mean = sums[512 + t] * (1.f / 65536.f);
        float var = sums[768 + t] * (1.f / 65536.f) - mean * mean;
        float sc = g_reg[t] * rsqrtf(var + 1e-5f);
        ss[512 + t] = sc;
        ss[768 + t] = b_reg[t] - mean * sc;
    }
}

// ---------------------------------------------------------------- lin_cls (y bf16)
__global__ __launch_bounds__(256) void k_lin_cls(const unsigned short* __restrict__ y, const float* __restrict__ ss,
                                                 const float* __restrict__ w, const float* __restrict__ bias,
                                                 float* __restrict__ out) {
    const int jt = blockIdx.x, n = blockIdx.y, j0 = jt * 16;
    const int tid = threadIdx.x;
    float part[16];
#pragma unroll
    for (int j = 0; j < 16; ++j) part[j] = 0.f;

    for (int s = 0; s < 8; ++s) {
        int k8 = (s * 256 + tid) * 8;
        short8 yv = *reinterpret_cast<const short8*>(&y[n * 16384 + k8]);
        int ch = k8 >> 6;
        float sc = ss[ch], sh = ss[256 + ch];
        float a_[8];
#pragma unroll
        for (int j = 0; j < 8; ++j)
            a_[j] = fmaxf(fmaf(bf2f((unsigned short)yv[j]), sc, sh), 0.f);
#pragma unroll
        for (int j = 0; j < 16; ++j) {
            const float* wp = &w[(j0 + j) * 16384 + k8];
            float4 w0 = *reinterpret_cast<const float4*>(wp);
            float4 w1 = *reinterpret_cast<const float4*>(wp + 4);
            float p = part[j];
            p = fmaf(a_[0], w0.x, p); p = fmaf(a_[1], w0.y, p);
            p = fmaf(a_[2], w0.z, p); p = fmaf(a_[3], w0.w, p);
            p = fmaf(a_[4], w1.x, p); p = fmaf(a_[5], w1.y, p);
            p = fmaf(a_[6], w1.z, p); p = fmaf(a_[7], w1.w, p);
            part[j] = p;
        }
    }
    __shared__ float red[16][4];
    const int lane = tid & 63, wid = tid >> 6;
#pragma unroll
    for (int j = 0; j < 16; ++j) {
        float v = part[j];
#pragma unroll
        for (int off = 1; off < 64; off <<= 1) v += __shfl_xor(v, off);
        if (lane == 0) red[j][wid] = v;
    }
    __syncthreads();
    if (tid < 16)
        out[n * 80 + j0 + tid] = red[tid][0] + red[tid][1] + red[tid][2] + red[tid][3] + bias[j0 + tid];
}

// ---------------------------------------------------------------- lin_reg (y bf16)
__global__ __launch_bounds__(256) void k_lin_reg(const unsigned short* __restrict__ y, const float* __restrict__ ss,
                                                 const float* __restrict__ w, float* __restrict__ out_loc) {
    __shared__ float a_s[64 * 65];
    __shared__ float w_s[160 * 65];
    const int jt = blockIdx.x & 1, ks = blockIdx.x >> 1;
    const int j0 = jt * 160, k0 = ks * 1024;
    const int tid = threadIdx.x;
    const int tj = tid & 31, tn = tid >> 5;
    float acc[5][8];
#pragma unroll
    for (int a = 0; a < 5; ++a)
#pragma unroll
        for (int b = 0; b < 8; ++b) acc[a][b] = 0.f;

    for (int st = 0; st < 16; ++st) {
        const int kb = k0 + st * 64;
        __syncthreads();
#pragma unroll
        for (int r = 0; r < 2; ++r) {
            int f = tid + 256 * r;
            int nn = f >> 3, k8l = (f & 7) * 8;
            short8 yv = *reinterpret_cast<const short8*>(&y[(size_t)nn * 262144 + kb + k8l]);
            int ch = (kb + k8l) >> 10;
            float sc = ss[512 + ch], sh = ss[768 + ch];
            float* dst = &a_s[nn * 65 + k8l];
#pragma unroll
            for (int j = 0; j < 8; ++j)
                dst[j] = fmaxf(fmaf(bf2f((unsigned short)yv[j]), sc, sh), 0.f);
        }
#pragma unroll
        for (int r = 0; r < 10; ++r) {
            int f = tid + 256 * r;
            int jl = f >> 4, kk4 = (f & 15) * 4;
            float4 wv = *reinterpret_cast<const float4*>(&w[(size_t)(j0 + jl) * 262144 + kb + kk4]);
            float* dst = &w_s[jl * 65 + kk4];
            dst[0] = wv.x; dst[1] = wv.y; dst[2] = wv.z; dst[3] = wv.w;
        }
        __syncthreads();
#pragma unroll 4
        for (int kk = 0; kk < 64; ++kk) {
            float av[8];
#pragma unroll
            for (int ii = 0; ii < 8; ++ii) av[ii] = a_s[(tn * 8 + ii) * 65 + kk];
#pragma unroll
            for (int jj = 0; jj < 5; ++jj) {
                float wvv = w_s[(tj + 32 * jj) * 65 + kk];
#pragma unroll
                for (int ii = 0; ii < 8; ++ii)
                    acc[jj][ii] = fmaf(wvv, av[ii], acc[jj][ii]);
            }
        }
    }
#pragma unroll
    for (int jj = 0; jj < 5; ++jj)
#pragma unroll
        for (int ii = 0; ii < 8; ++ii)
            atomicAdd(&out_loc[(tn * 8 + ii) * 320 + j0 + tj + 32 * jj], acc[jj][ii]);
}

// ---------------------------------------------------------------- launch
extern "C" void kernel_launch(void* const* d_in, const int* in_sizes, int n_in,
                              void* d_out, int out_size, void* d_ws, size_t ws_size,
                              hipStream_t stream) {
    const float* z_f        = (const float*)d_in[0];
    const float* x_f        = (const float*)d_in[1];
    const float* conv_cls_w = (const float*)d_in[2];
    const float* bn_cls_g   = (const float*)d_in[3];
    const float* bn_cls_b   = (const float*)d_in[4];
    const float* conv_reg_w = (const float*)d_in[5];
    const float* bn_reg_g   = (const float*)d_in[6];
    const float* bn_reg_b   = (const float*)d_in[7];
    const float* lin_cls_w  = (const float*)d_in[8];
    const float* lin_cls_b  = (const float*)d_in[9];
    const float* lin_reg_w  = (const float*)d_in[10];
    const float* lin_reg_b  = (const float*)d_in[11];

    float* out = (float*)d_out;
    float* ws  = (float*)d_ws;
    unsigned* ds_enc = (unsigned*)(ws + WS_DS_ENC);
    float* dist_t = ws + WS_DT;
    float* sums   = ws + WS_SUMS;
    float* ss     = ws + WS_SS;
    unsigned short* y_cls = (unsigned short*)(ws + WS_YCLS);
    unsigned short* y_reg = (unsigned short*)(ws + WS_YREG);
    unsigned short* xt    = (unsigned short*)(ws + WS_XT);
    unsigned short* zt    = (unsigned short*)(ws + WS_ZT);
    unsigned short* wtr   = (unsigned short*)(ws + WS_WTR);
    unsigned short* wtdr  = (unsigned short*)(ws + WS_WTDR);
    unsigned short* wtc   = (unsigned short*)(ws + WS_WTC);
    unsigned short* wtdc  = (unsigned short*)(ws + WS_WTDC);

    hipLaunchKernelGGL(k_init, dim3(80), dim3(256), 0, stream, ds_enc, sums, out + 5120, lin_reg_b);
    hipLaunchKernelGGL(k_xt, dim3(64, 32), dim3(256), 0, stream, x_f, xt);
    hipLaunchKernelGGL(k_zt, dim3(64), dim3(256), 0, stream, z_f, zt);
    hipLaunchKernelGGL(k_wswz, dim3(292, 2), dim3(256), 0, stream, conv_reg_w, conv_cls_w, wtr, wtdr, wtc, wtdc);
    hipLaunchKernelGGL(k_dist, dim3(4, 64), dim3(256), 0, stream, z_f, x_f, dist_t, ds_enc);
    hipLaunchKernelGGL(k_conv_reg, dim3(16, 64), dim3(256), 0, stream, xt, dist_t, wtr, wtdr, y_reg, sums);
    hipLaunchKernelGGL(k_conv_cls, dim3(32, 2), dim3(256), 0, stream, zt, ds_enc, wtc, wtdc, y_cls, sums);
    hipLaunchKernelGGL(k_bnfin, dim3(1), dim3(256), 0, stream, sums, bn_cls_g, bn_cls_b, bn_reg_g, bn_reg_b, ss);
    hipLaunchKernelGGL(k_lin_cls, dim3(5, 64), dim3(256), 0, stream, y_cls, ss, lin_cls_w, lin_cls_b, out);
    hipLaunchKernelGGL(k_lin_reg, dim3(512), dim3(256), 0, stream, y_reg, ss, lin_reg_w, out + 5120);
}

// Round 3
// 922.666 us; speedup vs baseline: 3.1766x; 1.0465x over previous
//
#include <hip/hip_runtime.h>
#include <math.h>

typedef short short8 __attribute__((ext_vector_type(8)));
typedef float f32x4 __attribute__((ext_vector_type(4)));
typedef unsigned int uint4v __attribute__((ext_vector_type(4)));

// ---------------- workspace layout (float offsets) ----------------
#define WS_DS_ENC 0            // 4096 u32
#define WS_DT     4096         // 65536 f32
#define WS_SUMS   69632        // 1024 f32
#define WS_SS     70656        // 1024 f32
#define WS_YCLS   71680        // 1,048,576 ushort (524288 fl)  [n][256][64] bf16
#define WS_YREG   595968       // 16,777,216 ushort (8388608 fl) [n][256][1024] bf16
#define WS_XT     8984576      // 16,777,216 ushort  [n][32][32][256] bf16
#define WS_ZT     17373184     // 1,048,576 ushort   [n][64][256] bf16
#define WS_WTR    17897472     // 589,824 ushort  [9][8][4][256][8]
#define WS_WTDR   18192384     // 8,192 ushort    [4][256][8]
#define WS_WTC    18196480     // 589,824 ushort
#define WS_WTDC   18491392     // 8,192 ushort
#define WS_PART   18495488     // 10,485,760 f32  [512][64][320] lin_reg partials
// end: 28,981,248 floats = 116 MB (ws is ~1.3 GB per poison WRITE_SIZE)

__device__ __forceinline__ float dsig(float d) {
    return 4.0f / (1.0f + __expf(d)) - 1.0f;   // monotone decreasing
}
__device__ __forceinline__ unsigned fenc(float f) {
    unsigned u = __float_as_uint(f);
    return (u & 0x80000000u) ? ~u : (u | 0x80000000u);
}
__device__ __forceinline__ float fdec(unsigned e) {
    unsigned u = (e & 0x80000000u) ? (e ^ 0x80000000u) : ~e;
    return __uint_as_float(u);
}
__device__ __forceinline__ unsigned short f2bf(float f) {   // RNE
    unsigned u = __float_as_uint(f);
    return (unsigned short)((u + 0x7fffu + ((u >> 16) & 1u)) >> 16);
}
__device__ __forceinline__ float bf2f(unsigned short h) {
    return __uint_as_float(((unsigned)h) << 16);
}
// truncating pack of 8 fp32 -> short8 bf16 (hi-half packing, ~2 VALU per pair)
__device__ __forceinline__ short8 pack8_trunc(const float* f) {
    uint4v u;
#pragma unroll
    for (int i = 0; i < 4; ++i) {
        unsigned lo = __float_as_uint(f[2 * i]) >> 16;
        unsigned hi = __float_as_uint(f[2 * i + 1]) & 0xffff0000u;
        u[i] = lo | hi;
    }
    return __builtin_bit_cast(short8, u);
}

// ---------------------------------------------------------------- init
__global__ void k_init(unsigned* __restrict__ ds_enc, float* __restrict__ sums,
                       float* __restrict__ out_loc, const float* __restrict__ lin_reg_b) {
    int i = blockIdx.x * 256 + threadIdx.x;
    if (i < 4096) ds_enc[i] = 0u;
    if (i < 1024) sums[i] = 0.0f;
    if (i < 20480) out_loc[i] = lin_reg_b[i % 320];
}

// ---------------------------------------------------------------- transposes
__global__ __launch_bounds__(256) void k_xt(const float* __restrict__ x, unsigned short* __restrict__ xt) {
    __shared__ float t[64 * 33];
    const int n = blockIdx.x, row = blockIdx.y;
    const int tid = threadIdx.x;
    for (int c4 = 0; c4 < 4; ++c4) {
        const int ic0 = c4 * 64;
        __syncthreads();
        {
            int icl = tid >> 2, cg = tid & 3;
            const float* src = &x[((n * 256 + ic0 + icl) * 32 + row) * 32 + cg * 8];
            float4 a = *reinterpret_cast<const float4*>(src);
            float4 b = *reinterpret_cast<const float4*>(src + 4);
            float* d = &t[icl * 33 + cg * 8];
            d[0] = a.x; d[1] = a.y; d[2] = a.z; d[3] = a.w;
            d[4] = b.x; d[5] = b.y; d[6] = b.z; d[7] = b.w;
        }
        __syncthreads();
        {
            int col = tid & 31, g = tid >> 5;
            short8 v;
#pragma unroll
            for (int j = 0; j < 8; ++j) v[j] = (short)f2bf(t[(g * 8 + j) * 33 + col]);
            *reinterpret_cast<short8*>(&xt[((n * 32 + row) * 32 + col) * 256 + ic0 + g * 8]) = v;
        }
    }
}

__global__ __launch_bounds__(256) void k_zt(const float* __restrict__ z, unsigned short* __restrict__ zt) {
    __shared__ float t[64 * 65];
    const int n = blockIdx.x;
    const int tid = threadIdx.x;
    for (int c4 = 0; c4 < 4; ++c4) {
        const int ic0 = c4 * 64;
        __syncthreads();
        {
            int icl = tid >> 2, pg = tid & 3;
            const float* src = &z[(n * 256 + ic0 + icl) * 64 + pg * 16];
#pragma unroll
            for (int r = 0; r < 4; ++r) {
                float4 a = *reinterpret_cast<const float4*>(src + r * 4);
                float* d = &t[icl * 65 + pg * 16 + r * 4];
                d[0] = a.x; d[1] = a.y; d[2] = a.z; d[3] = a.w;
            }
        }
        __syncthreads();
        {
            int pos = tid & 63, gg = tid >> 6;
            short8 v0, v1;
#pragma unroll
            for (int j = 0; j < 8; ++j) v0[j] = (short)f2bf(t[(gg * 16 + j) * 65 + pos]);
#pragma unroll
            for (int j = 0; j < 8; ++j) v1[j] = (short)f2bf(t[(gg * 16 + 8 + j) * 65 + pos]);
            unsigned short* d = &zt[(n * 64 + pos) * 256 + ic0 + gg * 16];
            *reinterpret_cast<short8*>(d) = v0;
            *reinterpret_cast<short8*>(d + 8) = v1;
        }
    }
}

// ---------------------------------------------------------------- weight swizzle
__global__ void k_wswz(const float* __restrict__ wr, const float* __restrict__ wc,
                       unsigned short* __restrict__ wtr, unsigned short* __restrict__ wtdr,
                       unsigned short* __restrict__ wtc, unsigned short* __restrict__ wtdc) {
    const int idx = blockIdx.x * 256 + threadIdx.x;
    const float* src = blockIdx.y ? wc : wr;
    unsigned short* dw = blockIdx.y ? wtc : wtr;
    unsigned short* dd = blockIdx.y ? wtdc : wtdr;
    if (idx < 73728) {
        int tap = idx >> 13, rem = idx & 8191;
        int kc = rem >> 10, rem2 = rem & 1023;
        int q = rem2 >> 8, oc = rem2 & 255;
        short8 v;
#pragma unroll
        for (int j = 0; j < 8; ++j) {
            int icg = 1 + kc * 32 + q * 8 + j;
            v[j] = (short)f2bf(src[(oc * 257 + icg) * 9 + tap]);
        }
        *reinterpret_cast<short8*>(&dw[idx * 8]) = v;
    } else if (idx < 74752) {
        int i2 = idx - 73728;
        int q = i2 >> 8, oc = i2 & 255;
        short8 v;
#pragma unroll
        for (int j = 0; j < 8; ++j) {
            int k = q * 8 + j;
            v[j] = (k < 9) ? (short)f2bf(src[(oc * 257) * 9 + k]) : (short)0;
        }
        *reinterpret_cast<short8*>(&dd[i2 * 8]) = v;
    }
}

// ---------------------------------------------------------------- dist
__global__ __launch_bounds__(256) void k_dist(const float* __restrict__ z, const float* __restrict__ x,
                                              float* __restrict__ dist_t, unsigned* __restrict__ ds_enc) {
    __shared__ float zsq_s[64];
    const int n = blockIdx.y;
    const int q = (blockIdx.x << 8) + threadIdx.x;
    const float* zb = z + n * 16384;
    const float* xb = x + n * 262144;

    if (threadIdx.x < 64) {
        int p = threadIdx.x;
        float s = 0.f;
        for (int c = 0; c < 256; ++c) { float v = zb[c * 64 + p]; s = fmaf(v, v, s); }
        zsq_s[p] = s;
    }
    __syncthreads();

    float4 acc[16];
#pragma unroll
    for (int i = 0; i < 16; ++i) acc[i] = make_float4(0.f, 0.f, 0.f, 0.f);
    float xsq = 0.f;
    for (int c = 0; c < 256; ++c) {
        float xv = xb[c * 1024 + q];
        xsq = fmaf(xv, xv, xsq);
        const float4* z4 = reinterpret_cast<const float4*>(zb + c * 64);
#pragma unroll
        for (int i = 0; i < 16; ++i) {
            float4 zv = z4[i];
            acc[i].x = fmaf(zv.x, xv, acc[i].x);
            acc[i].y = fmaf(zv.y, xv, acc[i].y);
            acc[i].z = fmaf(zv.z, xv, acc[i].z);
            acc[i].w = fmaf(zv.w, xv, acc[i].w);
        }
    }

    const int lane = threadIdx.x & 63;
    float dmax = -1e30f;
    auto do_p = [&](int p, float a) {
        float dr = zsq_s[p] + xsq - 2.f * a;
        dmax = fmaxf(dmax, dr);
        float m = dr;
#pragma unroll
        for (int off = 1; off < 64; off <<= 1) m = fmaxf(m, __shfl_xor(m, off));
        if (lane == 0) atomicMax(&ds_enc[n * 64 + p], fenc(m));
    };
#pragma unroll
    for (int i = 0; i < 16; ++i) {
        do_p(4 * i + 0, acc[i].x);
        do_p(4 * i + 1, acc[i].y);
        do_p(4 * i + 2, acc[i].z);
        do_p(4 * i + 3, acc[i].w);
    }
    dist_t[n * 1024 + q] = dsig(dmax);
}

// ---------------------------------------------------------------- conv_reg MFMA
__global__ __launch_bounds__(256) void k_conv_reg(
    const unsigned short* __restrict__ xt, const float* __restrict__ dist_t,
    const unsigned short* __restrict__ wt, const unsigned short* __restrict__ wtd,
    unsigned short* __restrict__ y, float* __restrict__ sums) {
    __shared__ __align__(16) char smem[17408];
    unsigned short* As = (unsigned short*)smem;              // 204*40
    unsigned short* Ds = (unsigned short*)(smem + 16320);    // 204
    float* Ts = (float*)smem;                                // 4*1088 after barrier

    const int n = blockIdx.y;
    const int pt = blockIdx.x >> 1, ot = blockIdx.x & 1;
    const int tid = threadIdx.x;
    const int w = tid >> 6, lane = tid & 63;
    const int l15 = lane & 15, q = lane >> 4;
    const int wm = w & 1, wn = w >> 1;
    const int ocW = ot * 128 + wn * 64;

    f32x4 acc[4][4];
#pragma unroll
    for (int mi = 0; mi < 4; ++mi)
#pragma unroll
        for (int ni = 0; ni < 4; ++ni) acc[mi][ni] = (f32x4){0.f, 0.f, 0.f, 0.f};

    for (int f = tid; f < 204; f += 256) {
        int rr = f / 34, cc = f % 34;
        int prow = pt * 4 + rr;
        float v = 0.f;
        if (prow >= 1 && prow <= 32 && cc >= 1 && cc <= 32)
            v = dist_t[n * 1024 + (prow - 1) * 32 + (cc - 1)];
        Ds[f] = f2bf(v);
    }
    __syncthreads();
    {
        short8 ad[4];
#pragma unroll
        for (int mi = 0; mi < 4; ++mi) {
            int m = wm * 64 + mi * 16 + l15;
            int r = m >> 5, c = m & 31;
            short8 v = {0, 0, 0, 0, 0, 0, 0, 0};
#pragma unroll
            for (int j = 0; j < 8; ++j) {
                int k = q * 8 + j;
                if (k < 9) {
                    int ky = k / 3, kx = k % 3;
                    v[j] = (short)Ds[(r + ky) * 34 + (c + kx)];
                }
            }
            ad[mi] = v;
        }
#pragma unroll
        for (int ni = 0; ni < 4; ++ni) {
            short8 b = *reinterpret_cast<const short8*>(&wtd[(q * 256 + ocW + ni * 16 + l15) * 8]);
#pragma unroll
            for (int mi = 0; mi < 4; ++mi)
                acc[mi][ni] = __builtin_amdgcn_mfma_f32_16x16x32_bf16(ad[mi], b, acc[mi][ni], 0, 0, 0);
        }
    }

    for (int kc = 0; kc < 8; ++kc) {
        __syncthreads();
#pragma unroll
        for (int it = 0; it < 4; ++it) {
            int f = tid + 256 * it;
            if (f < 816) {
                int cell = f >> 2, ch = f & 3;
                int rr = cell / 34, cc = cell % 34;
                int prow = pt * 4 + rr;
                short8 v = {0, 0, 0, 0, 0, 0, 0, 0};
                if (prow >= 1 && prow <= 32 && cc >= 1 && cc <= 32)
                    v = *reinterpret_cast<const short8*>(
                        &xt[((n * 32 + prow - 1) * 32 + cc - 1) * 256 + kc * 32 + ch * 8]);
                *reinterpret_cast<short8*>(&As[cell * 40 + ch * 8]) = v;
            }
        }
        __syncthreads();
#pragma unroll
        for (int tap = 0; tap < 9; ++tap) {
            const int ky = tap / 3, kx = tap % 3;
            short8 a[4];
#pragma unroll
            for (int mi = 0; mi < 4; ++mi) {
                int m = wm * 64 + mi * 16 + l15;
                int r = (m >> 5) + ky, c = (m & 31) + kx;
                a[mi] = *reinterpret_cast<const short8*>(&As[(r * 34 + c) * 40 + q * 8]);
            }
            const unsigned short* wb = wt + (size_t)(((tap * 8 + kc) * 4 + q) * 256) * 8;
#pragma unroll
            for (int ni = 0; ni < 4; ++ni) {
                short8 b = *reinterpret_cast<const short8*>(&wb[(ocW + ni * 16 + l15) * 8]);
#pragma unroll
                for (int mi = 0; mi < 4; ++mi)
                    acc[mi][ni] = __builtin_amdgcn_mfma_f32_16x16x32_bf16(a[mi], b, acc[mi][ni], 0, 0, 0);
            }
        }
    }

#pragma unroll
    for (int ni = 0; ni < 4; ++ni) {
        float s = 0.f, qq = 0.f;
#pragma unroll
        for (int mi = 0; mi < 4; ++mi)
#pragma unroll
            for (int e = 0; e < 4; ++e) {
                float v = acc[mi][ni][e];
                s += v; qq = fmaf(v, v, qq);
            }
        s += __shfl_xor(s, 16); s += __shfl_xor(s, 32);
        qq += __shfl_xor(qq, 16); qq += __shfl_xor(qq, 32);
        if (lane < 16) {
            atomicAdd(&sums[512 + ocW + ni * 16 + l15], s);
            atomicAdd(&sums[768 + ocW + ni * 16 + l15], qq);
        }
    }

    __syncthreads();
    float* T = Ts + w * 1088;
#pragma unroll
    for (int mi = 0; mi < 4; ++mi) {
#pragma unroll
        for (int ni = 0; ni < 4; ++ni)
#pragma unroll
            for (int e = 0; e < 4; ++e)
                T[(ni * 16 + l15) * 17 + q * 4 + e] = acc[mi][ni][e];
#pragma unroll
        for (int eo = 0; eo < 16; ++eo) {
            int ocl = eo * 4 + q;
            float v = T[ocl * 17 + l15];
            y[(size_t)n * 262144 + (size_t)(ocW + ocl) * 1024 + pt * 128 + wm * 64 + mi * 16 + l15] = f2bf(v);
        }
    }
}

// ---------------------------------------------------------------- conv_cls MFMA
__global__ __launch_bounds__(256) void k_conv_cls(
    const unsigned short* __restrict__ zt, const unsigned* __restrict__ ds_enc,
    const unsigned short* __restrict__ wt, const unsigned short* __restrict__ wtd,
    unsigned short* __restrict__ y, float* __restrict__ sums) {
    __shared__ __align__(16) char smem[17408];
    unsigned short* As = (unsigned short*)smem;
    unsigned short* Ds = (unsigned short*)(smem + 16000);
    float* Ts = (float*)smem;

    const int n0 = blockIdx.x * 2;
    const int ob = blockIdx.y;
    const int tid = threadIdx.x;
    const int w = tid >> 6, lane = tid & 63;
    const int l15 = lane & 15, q = lane >> 4;
    const int wm = w & 1, wn = w >> 1;
    const int ocW = ob * 128 + wn * 64;

    f32x4 acc[4][4];
#pragma unroll
    for (int mi = 0; mi < 4; ++mi)
#pragma unroll
        for (int ni = 0; ni < 4; ++ni) acc[mi][ni] = (f32x4){0.f, 0.f, 0.f, 0.f};

    for (int f = tid; f < 200; f += 256) {
        int n_l = f / 100, rem = f % 100;
        int rr = rem / 10, cc = rem % 10;
        float v = 0.f;
        if (rr >= 1 && rr <= 8 && cc >= 1 && cc <= 8)
            v = dsig(fdec(ds_enc[(n0 + n_l) * 64 + (rr - 1) * 8 + (cc - 1)]));
        Ds[f] = f2bf(v);
    }
    __syncthreads();
    {
        short8 ad[4];
#pragma unroll
        for (int mi = 0; mi < 4; ++mi) {
            int pos = mi * 16 + l15;
            int r = pos >> 3, c = pos & 7;
            short8 v = {0, 0, 0, 0, 0, 0, 0, 0};
#pragma unroll
            for (int j = 0; j < 8; ++j) {
                int k = q * 8 + j;
                if (k < 9) {
                    int ky = k / 3, kx = k % 3;
                    v[j] = (short)Ds[wm * 100 + (r + ky) * 10 + (c + kx)];
                }
            }
            ad[mi] = v;
        }
#pragma unroll
        for (int ni = 0; ni < 4; ++ni) {
            short8 b = *reinterpret_cast<const short8*>(&wtd[(q * 256 + ocW + ni * 16 + l15) * 8]);
#pragma unroll
            for (int mi = 0; mi < 4; ++mi)
                acc[mi][ni] = __builtin_amdgcn_mfma_f32_16x16x32_bf16(ad[mi], b, acc[mi][ni], 0, 0, 0);
        }
    }

    for (int kc = 0; kc < 8; ++kc) {
        __syncthreads();
#pragma unroll
        for (int it = 0; it < 4; ++it) {
            int f = tid + 256 * it;
            if (f < 800) {
                int cell = f >> 2, ch = f & 3;
                int n_l = cell / 100, rem = cell % 100;
                int rr = rem / 10, cc = rem % 10;
                short8 v = {0, 0, 0, 0, 0, 0, 0, 0};
                if (rr >= 1 && rr <= 8 && cc >= 1 && cc <= 8)
                    v = *reinterpret_cast<const short8*>(
                        &zt[((n0 + n_l) * 64 + (rr - 1) * 8 + (cc - 1)) * 256 + kc * 32 + ch * 8]);
                *reinterpret_cast<short8*>(&As[cell * 40 + ch * 8]) = v;
            }
        }
        __syncthreads();
#pragma unroll
        for (int tap = 0; tap < 9; ++tap) {
            const int ky = tap / 3, kx = tap % 3;
            short8 a[4];
#pragma unroll
            for (int mi = 0; mi < 4; ++mi) {
                int pos = mi * 16 + l15;
                int r = (pos >> 3) + ky, c = (pos & 7) + kx;
                a[mi] = *reinterpret_cast<const short8*>(&As[(wm * 100 + r * 10 + c) * 40 + q * 8]);
            }
            const unsigned short* wb = wt + (size_t)(((tap * 8 + kc) * 4 + q) * 256) * 8;
#pragma unroll
            for (int ni = 0; ni < 4; ++ni) {
                short8 b = *reinterpret_cast<const short8*>(&wb[(ocW + ni * 16 + l15) * 8]);
#pragma unroll
                for (int mi = 0; mi < 4; ++mi)
                    acc[mi][ni] = __builtin_amdgcn_mfma_f32_16x16x32_bf16(a[mi], b, acc[mi][ni], 0, 0, 0);
            }
        }
    }

#pragma unroll
    for (int ni = 0; ni < 4; ++ni) {
        float s = 0.f, qq = 0.f;
#pragma unroll
        for (int mi = 0; mi < 4; ++mi)
#pragma unroll
            for (int e = 0; e < 4; ++e) {
                float v = acc[mi][ni][e];
                s += v; qq = fmaf(v, v, qq);
            }
        s += __shfl_xor(s, 16); s += __shfl_xor(s, 32);
        qq += __shfl_xor(qq, 16); qq += __shfl_xor(qq, 32);
        if (lane < 16) {
            atomicAdd(&sums[0 + ocW + ni * 16 + l15], s);
            atomicAdd(&sums[256 + ocW + ni * 16 + l15], qq);
        }
    }

    __syncthreads();
    float* T = Ts + w * 1088;
#pragma unroll
    for (int mi = 0; mi < 4; ++mi) {
#pragma unroll
        for (int ni = 0; ni < 4; ++ni)
#pragma unroll
            for (int e = 0; e < 4; ++e)
                T[(ni * 16 + l15) * 17 + q * 4 + e] = acc[mi][ni][e];
#pragma unroll
        for (int eo = 0; eo < 16; ++eo) {
            int ocl = eo * 4 + q;
            float v = T[ocl * 17 + l15];
            y[(size_t)(n0 + wm) * 16384 + (size_t)(ocW + ocl) * 64 + mi * 16 + l15] = f2bf(v);
        }
    }
}

// ---------------------------------------------------------------- BN finalize
__global__ void k_bnfin(const float* __restrict__ sums,
                        const float* __restrict__ g_cls, const float* __restrict__ b_cls,
                        const float* __restrict__ g_reg, const float* __restrict__ b_reg,
                        float* __restrict__ ss) {
    int t = threadIdx.x;
    {
        float mean = sums[t] * (1.f / 4096.f);
        float var = sums[256 + t] * (1.f / 4096.f) - mean * mean;
        float sc = g_cls[t] * rsqrtf(var + 1e-5f);
        ss[t] = sc;
        ss[256 + t] = b_cls[t] - mean * sc;
    }
    {
        float mean = sums[512 + t] * (1.f / 65536.f);
        float var = sums[768 + t] * (1.f / 65536.f) - mean * mean;
        float sc = g_reg[t] * rsqrtf(var + 1e-5f);
        ss[512 + t] = sc;
        ss[768 + t] = b_reg[t] - mean * sc;
    }
}

// ---------------------------------------------------------------- lin_cls (y bf16)
__global__ __launch_bounds__(256) void k_lin_cls(const unsigned short* __restrict__ y, const float* __restrict__ ss,
                                                 const float* __restrict__ w, const float* __restrict__ bias,
                                                 float* __restrict__ out) {
    const int jt = blockIdx.x, n = blockIdx.y, j0 = jt * 16;
    const int tid = threadIdx.x;
    float part[16];
#pragma unroll
    for (int j = 0; j < 16; ++j) part[j] = 0.f;

    for (int s = 0; s < 8; ++s) {
        int k8 = (s * 256 + tid) * 8;
        short8 yv = *reinterpret_cast<const short8*>(&y[n * 16384 + k8]);
        int ch = k8 >> 6;
        float sc = ss[ch], sh = ss[256 + ch];
        float a_[8];
#pragma unroll
        for (int j = 0; j < 8; ++j)
            a_[j] = fmaxf(fmaf(bf2f((unsigned short)yv[j]), sc, sh), 0.f);
#pragma unroll
        for (int j = 0; j < 16; ++j) {
            const float* wp = &w[(j0 + j) * 16384 + k8];
            float4 w0 = *reinterpret_cast<const float4*>(wp);
            float4 w1 = *reinterpret_cast<const float4*>(wp + 4);
            float p = part[j];
            p = fmaf(a_[0], w0.x, p); p = fmaf(a_[1], w0.y, p);
            p = fmaf(a_[2], w0.z, p); p = fmaf(a_[3], w0.w, p);
            p = fmaf(a_[4], w1.x, p); p = fmaf(a_[5], w1.y, p);
            p = fmaf(a_[6], w1.z, p); p = fmaf(a_[7], w1.w, p);
            part[j] = p;
        }
    }
    __shared__ float red[16][4];
    const int lane = tid & 63, wid = tid >> 6;
#pragma unroll
    for (int j = 0; j < 16; ++j) {
        float v = part[j];
#pragma unroll
        for (int off = 1; off < 64; off <<= 1) v += __shfl_xor(v, off);
        if (lane == 0) red[j][wid] = v;
    }
    __syncthreads();
    if (tid < 16)
        out[n * 80 + j0 + tid] = red[tid][0] + red[tid][1] + red[tid][2] + red[tid][3] + bias[j0 + tid];
}

// ---------------------------------------------------------------- lin_reg MFMA (streaming W)
// grid 512 k-splits (512 k each). Block 256 thr = 4 waves; wave w owns j in [80w, 80w+80).
// W (fp32, 335 MB) -> registers -> bf16 trunc -> B-frags; read exactly once, no LDS.
// A (y_reg bf16) staged per 256-k subchunk into LDS in frag order with scalar norm+relu.
__global__ __launch_bounds__(256) void k_lin_reg2(const unsigned short* __restrict__ y, const float* __restrict__ ss,
                                                  const float* __restrict__ w, float* __restrict__ part) {
    __shared__ __align__(16) unsigned short A_l[32 * 520];   // 32 regions x (64n x 8 bf16 + 8 pad)
    const int k0 = blockIdx.x * 512;
    const int tid = threadIdx.x;
    const int wv = tid >> 6, lane = tid & 63;
    const int l15 = lane & 15, q = lane >> 4;
    const int jw = wv * 80;

    f32x4 acc[5][4];
#pragma unroll
    for (int ni = 0; ni < 5; ++ni)
#pragma unroll
        for (int mi = 0; mi < 4; ++mi) acc[ni][mi] = (f32x4){0.f, 0.f, 0.f, 0.f};

    for (int scn = 0; scn < 2; ++scn) {
        const int ksub = k0 + scn * 256;
        const int ch = ksub >> 10;
        const float scf = ss[512 + ch], shf = ss[768 + ch];
        __syncthreads();
        // stage A: 64 n x 256 k, norm+relu, frag-order layout [c][n][8]
        {
            const int c = tid & 31, nb = tid >> 5;
#pragma unroll
            for (int p = 0; p < 8; ++p) {
                const int n = p * 8 + nb;
                short8 v = *reinterpret_cast<const short8*>(&y[(size_t)n * 262144 + ksub + c * 8]);
                float f[8];
#pragma unroll
                for (int j = 0; j < 8; ++j)
                    f[j] = fmaxf(fmaf(bf2f((unsigned short)v[j]), scf, shf), 0.f);
                *reinterpret_cast<short8*>(&A_l[c * 520 + n * 8]) = pack8_trunc(f);
            }
        }
        __syncthreads();
#pragma unroll
        for (int kk = 0; kk < 8; ++kk) {
            short8 a[4];
#pragma unroll
            for (int mi = 0; mi < 4; ++mi)
                a[mi] = *reinterpret_cast<const short8*>(&A_l[(kk * 4 + q) * 520 + (mi * 16 + l15) * 8]);
            short8 b[5];
#pragma unroll
            for (int ni = 0; ni < 5; ++ni) {
                const float* wp = &w[(size_t)(jw + ni * 16 + l15) * 262144 + ksub + kk * 32 + q * 8];
                float4 b0 = *reinterpret_cast<const float4*>(wp);
                float4 b1 = *reinterpret_cast<const float4*>(wp + 4);
                float f[8] = {b0.x, b0.y, b0.z, b0.w, b1.x, b1.y, b1.z, b1.w};
                b[ni] = pack8_trunc(f);
            }
#pragma unroll
            for (int ni = 0; ni < 5; ++ni)
#pragma unroll
                for (int mi = 0; mi < 4; ++mi)
                    acc[ni][mi] = __builtin_amdgcn_mfma_f32_16x16x32_bf16(a[mi], b[ni], acc[ni][mi], 0, 0, 0);
        }
    }

    // write partials [blk][n][j]: wave owns j-range exclusively, no atomics
    float* pb = part + (size_t)blockIdx.x * 20480;
#pragma unroll
    for (int ni = 0; ni < 5; ++ni) {
        const int j = jw + ni * 16 + l15;
#pragma unroll
        for (int mi = 0; mi < 4; ++mi)
#pragma unroll
            for (int e = 0; e < 4; ++e) {
                const int n = mi * 16 + q * 4 + e;
                pb[n * 320 + j] = acc[ni][mi][e];
            }
    }
}

// reduce: out[n][j] (+= bias, pre-seeded) over 512 partial blocks; grid (80, 4)
__global__ __launch_bounds__(256) void k_lin_red(const float* __restrict__ part, float* __restrict__ out_loc) {
    const int idx = blockIdx.x * 256 + threadIdx.x;       // 0..20479
    const int b0 = blockIdx.y * 128;
    float s0 = 0.f, s1 = 0.f, s2 = 0.f, s3 = 0.f;
#pragma unroll 4
    for (int b = 0; b < 128; b += 4) {
        s0 += part[(size_t)(b0 + b + 0) * 20480 + idx];
        s1 += part[(size_t)(b0 + b + 1) * 20480 + idx];
        s2 += part[(size_t)(b0 + b + 2) * 20480 + idx];
        s3 += part[(size_t)(b0 + b + 3) * 20480 + idx];
    }
    atomicAdd(&out_loc[idx], (s0 + s1) + (s2 + s3));
}

// ---------------------------------------------------------------- launch
extern "C" void kernel_launch(void* const* d_in, const int* in_sizes, int n_in,
                              void* d_out, int out_size, void* d_ws, size_t ws_size,
                              hipStream_t stream) {
    const float* z_f        = (const float*)d_in[0];
    const float* x_f        = (const float*)d_in[1];
    const float* conv_cls_w = (const float*)d_in[2];
    const float* bn_cls_g   = (const float*)d_in[3];
    const float* bn_cls_b   = (const float*)d_in[4];
    const float* conv_reg_w = (const float*)d_in[5];
    const float* bn_reg_g   = (const float*)d_in[6];
    const float* bn_reg_b   = (const float*)d_in[7];
    const float* lin_cls_w  = (const float*)d_in[8];
    const float* lin_cls_b  = (const float*)d_in[9];
    const float* lin_reg_w  = (const float*)d_in[10];
    const float* lin_reg_b  = (const float*)d_in[11];

    float* out = (float*)d_out;
    float* ws  = (float*)d_ws;
    unsigned* ds_enc = (unsigned*)(ws + WS_DS_ENC);
    float* dist_t = ws + WS_DT;
    float* sums   = ws + WS_SUMS;
    float* ss     = ws + WS_SS;
    unsigned short* y_cls = (unsigned short*)(ws + WS_YCLS);
    unsigned short* y_reg = (unsigned short*)(ws + WS_YREG);
    unsigned short* xt    = (unsigned short*)(ws + WS_XT);
    unsigned short* zt    = (unsigned short*)(ws + WS_ZT);
    unsigned short* wtr   = (unsigned short*)(ws + WS_WTR);
    unsigned short* wtdr  = (unsigned short*)(ws + WS_WTDR);
    unsigned short* wtc   = (unsigned short*)(ws + WS_WTC);
    unsigned short* wtdc  = (unsigned short*)(ws + WS_WTDC);
    float* part   = ws + WS_PART;

    hipLaunchKernelGGL(k_init, dim3(80), dim3(256), 0, stream, ds_enc, sums, out + 5120, lin_reg_b);
    hipLaunchKernelGGL(k_xt, dim3(64, 32), dim3(256), 0, stream, x_f, xt);
    hipLaunchKernelGGL(k_zt, dim3(64), dim3(256), 0, stream, z_f, zt);
    hipLaunchKernelGGL(k_wswz, dim3(292, 2), dim3(256), 0, stream, conv_reg_w, conv_cls_w, wtr, wtdr, wtc, wtdc);
    hipLaunchKernelGGL(k_dist, dim3(4, 64), dim3(256), 0, stream, z_f, x_f, dist_t, ds_enc);
    hipLaunchKernelGGL(k_conv_reg, dim3(16, 64), dim3(256), 0, stream, xt, dist_t, wtr, wtdr, y_reg, sums);
    hipLaunchKernelGGL(k_conv_cls, dim3(32, 2), dim3(256), 0, stream, zt, ds_enc, wtc, wtdc, y_cls, sums);
    hipLaunchKernelGGL(k_bnfin, dim3(1), dim3(256), 0, stream, sums, bn_cls_g, bn_cls_b, bn_reg_g, bn_reg_b, ss);
    hipLaunchKernelGGL(k_lin_cls, dim3(5, 64), dim3(256), 0, stream, y_cls, ss, lin_cls_w, lin_cls_b, out);
    hipLaunchKernelGGL(k_lin_reg2, dim3(512), dim3(256), 0, stream, y_reg, ss, lin_reg_w, part);
    hipLaunchKernelGGL(k_lin_red, dim3(80, 4), dim3(256), 0, stream, part, out + 5120);
}